// Round 14
// baseline (369.254 us; speedup 1.0000x reference)
//
#include <hip/hip_runtime.h>

#define NN 10000
#define MP 10112      // 79*128, padded row count for MFMA GEMM A-tiles
#define EE 100000
#define ETOT 110000   // EE + NN self loops
#define INC 256
#define HH 6
#define CC 128
#define FF 768        // HH*CC
#define BB 64
#define BN_EPS 1e-5f

typedef unsigned short ushort_t;
typedef unsigned int uint_t;
typedef __attribute__((ext_vector_type(8))) short bf16x8;
typedef __attribute__((ext_vector_type(4))) float f32x4;
#define AS1 __attribute__((address_space(1)))
#define AS3 __attribute__((address_space(3)))

// ---------- float <-> order-preserving uint encoding (for atomicMax on float) ----------
// fenc(v) > 0 for every non-NaN v, so zero-initialized buffer acts as -inf.
__device__ __forceinline__ unsigned fenc(float v){
  unsigned u = __float_as_uint(v);
  return (u & 0x80000000u) ? ~u : (u | 0x80000000u);
}
__device__ __forceinline__ float fdec(unsigned u){
  return (u & 0x80000000u) ? __uint_as_float(u & 0x7FFFFFFFu) : __uint_as_float(~u);
}

__device__ __forceinline__ ushort_t f2bf(float v){   // RNE fp32 -> bf16
  unsigned u = __float_as_uint(v);
  u += 0x7FFFu + ((u >> 16) & 1u);
  return (ushort_t)(u >> 16);
}
__device__ __forceinline__ float bf_lo(uint_t u){ return __uint_as_float(u << 16); }
__device__ __forceinline__ float bf_hi(uint_t u){ return __uint_as_float(u & 0xFFFF0000u); }

__device__ __forceinline__ float bn_scale(const float* sums, const float* sumsq,
                                          const float* g, int k){
  float mu  = sums[k] * (1.f/NN);
  float var = sumsq[k] * (1.f/NN) - mu*mu;
  return g[k] * rsqrtf(var + BN_EPS);
}

// ---------- prep: count_deg + transpose(W1) + feat->bf16, fused (independent parts) ----------
#define PREP_CNT 430                 // ceil(ETOT/256)
#define PREP_TR  (24*8)              // (FF/32)*(INC/32)
#define PREP_CVT 2500                // NN*INC/4/256
__global__ __launch_bounds__(256) void prep(const int* __restrict__ adj, int* __restrict__ deg,
                                            const float* __restrict__ W1, ushort_t* __restrict__ W1t,
                                            const float* __restrict__ feat, ushort_t* __restrict__ featB){
  __shared__ ushort_t tile[32][33];
  int bid = blockIdx.x, tid = threadIdx.x;
  if(bid < PREP_CNT){
    int k = bid*256 + tid;
    if(k < ETOT){
      int d = (k < EE) ? adj[EE + k] : (k - EE);
      atomicAdd(deg + d, 1);
    }
  } else if(bid < PREP_CNT + PREP_TR){
    int b = bid - PREP_CNT;
    int nb = (b % 24)*32, kb = (b / 24)*32;    // K=INC rows, N=FF cols
    int tx = tid & 31, ty = tid >> 5;
    #pragma unroll
    for(int r = ty; r < 32; r += 8)
      tile[tx][r] = f2bf(W1[(size_t)(kb + r)*FF + nb + tx]);
    __syncthreads();
    #pragma unroll
    for(int r = ty; r < 32; r += 8)
      W1t[(size_t)(nb + r)*INC + kb + tx] = tile[r][tx];
  } else {
    int i = (bid - PREP_CNT - PREP_TR)*256 + tid;   // i < NN*INC/4 guaranteed by grid
    float4 v = ((const float4*)feat)[i];
    ushort4 o;
    o.x = f2bf(v.x); o.y = f2bf(v.y); o.z = f2bf(v.z); o.w = f2bf(v.w);
    ((ushort4*)featB)[i] = o;
  }
}

// ---------- CSR build ----------
__global__ __launch_bounds__(1024) void scan_deg(const int* __restrict__ deg,
                                                 int* __restrict__ row_start,
                                                 int* __restrict__ pos){
  __shared__ int wsum[16];
  __shared__ int wexcl[16];
  __shared__ int carry, ctot;
  int t = threadIdx.x, wave = t >> 6, lane = t & 63;
  if(t == 0) carry = 0;
  __syncthreads();
  for(int base = 0; base < NN; base += 1024){
    int i = base + t;
    int v = (i < NN) ? deg[i] : 0;
    int s = v;
    #pragma unroll
    for(int off = 1; off < 64; off <<= 1){ int x = __shfl_up(s, off); if(lane >= off) s += x; }
    if(lane == 63) wsum[wave] = s;
    __syncthreads();
    if(t < 16){
      int ws = wsum[t], sc = ws;
      #pragma unroll
      for(int off = 1; off < 16; off <<= 1){ int x = __shfl_up(sc, off); if(t >= off) sc += x; }
      wexcl[t] = sc - ws;
      if(t == 15) ctot = sc;
    }
    __syncthreads();
    int c = carry;
    if(i < NN){ int excl = c + wexcl[wave] + s - v; row_start[i] = excl; pos[i] = excl; }
    __syncthreads();
    if(t == 0) carry = c + ctot;
  }
  __syncthreads();
  if(t == 0) row_start[NN] = carry;
}

__global__ __launch_bounds__(256) void scatter_edges(const int* __restrict__ adj,
                                                     int* __restrict__ pos,
                                                     int* __restrict__ csr_src){
  int k = blockIdx.x*256 + threadIdx.x;
  if(k >= ETOT) return;
  int s, d;
  if(k < EE){ s = adj[k]; d = adj[EE + k]; } else { s = k - EE; d = s; }
  int i = atomicAdd(pos + d, 1);
  csr_src[i] = s;
}

// ---------- wfold: BN-scaled transpose + BN-shift bias fold, fused ----------
__global__ __launch_bounds__(256) void wfold(const float* __restrict__ W,
                                             int K, int N,
                                             const float* __restrict__ sums,
                                             const float* __restrict__ sumsq,
                                             const float* __restrict__ g,
                                             const float* __restrict__ be,
                                             const float* __restrict__ base,
                                             ushort_t* __restrict__ Wt,
                                             float* __restrict__ biasOut){
  __shared__ ushort_t tile[32][33];
  int nT = (K >> 5)*(N >> 5);
  int bid = blockIdx.x, tid = threadIdx.x;
  if(bid < nT){
    int nb = (bid % (N >> 5))*32, kb = (bid / (N >> 5))*32;
    int tx = tid & 31, ty = tid >> 5;
    #pragma unroll
    for(int r = ty; r < 32; r += 8){
      int k = kb + r;
      tile[tx][r] = f2bf(W[(size_t)k*N + nb + tx] * bn_scale(sums, sumsq, g, k));
    }
    __syncthreads();
    #pragma unroll
    for(int r = ty; r < 32; r += 8)
      Wt[(size_t)(nb + r)*K + kb + tx] = tile[r][tx];
  } else {
    int b = bid - nT;
    int oChunks = (N + 255) >> 8;
    int kc = b / oChunks, oc = b % oChunks;
    int o = oc*256 + tid;
    if(o >= N) return;
    int k0 = kc*64, k1 = k0 + 64;
    float s = 0.f;
    for(int k = k0; k < k1; k++){
      float mu = sums[k] * (1.f/NN);
      float sc = bn_scale(sums, sumsq, g, k);
      s = fmaf(be[k] - mu*sc, W[(size_t)k*N + o], s);
    }
    if(k0 == 0 && base) s += base[o];
    atomicAdd(biasOut + o, s);
  }
}

// ---------- bf16 MFMA GEMM + fused attention-dot epilogue (conv layers) ----------
// C[M,N] = A[MP,K] * Bt[N,K]^T (+bias); block cols = one head when atts!=null.
// C-store: 2-pass LDS staging (64 rows x 128 cols, stride 136) -> dwordx4 stores;
// att dots read rows back from LDS (4 thr/row + 2 shfl).
#define CTS 136
__global__ __launch_bounds__(256) void gemm_bt(const ushort_t* __restrict__ A,
                                               const ushort_t* __restrict__ Bt,
                                               ushort_t* __restrict__ Cb,
                                               int M, int N, int K,
                                               const float* __restrict__ bias,
                                               const float* __restrict__ atts,
                                               const float* __restrict__ attd,
                                               float* __restrict__ a_s,
                                               float* __restrict__ a_d){
  __shared__ ushort_t smem[8704];           // As[4096] | Bs[4096]; reused as Ct[64*136]
  ushort_t* As = smem;
  ushort_t* Bs = smem + 4096;
  int tid = threadIdx.x;
  int bm = blockIdx.y*128, bn = blockIdx.x*128;
  int w = tid >> 6, lane = tid & 63;
  int wr = (w >> 1)*64, wc = (w & 1)*64;
  int quad = lane >> 4, l15 = lane & 15;

  f32x4 acc[4][4];
  #pragma unroll
  for(int i=0;i<4;i++)
    #pragma unroll
    for(int j=0;j<4;j++) acc[i][j] = (f32x4){0.f,0.f,0.f,0.f};

  int ch0 = tid, ch1 = tid + 256;
  int ar0 = ch0 >> 2, ac0 = (ch0 & 3) << 3;
  int ar1 = ch1 >> 2, ac1 = (ch1 & 3) << 3;
  const ushort_t* Ag0 = A + (size_t)(bm + ar0)*K + ac0;
  const ushort_t* Ag1 = A + (size_t)(bm + ar1)*K + ac1;
  const ushort_t* Bg0 = Bt + (size_t)(bn + ar0)*K + ac0;
  const ushort_t* Bg1 = Bt + (size_t)(bn + ar1)*K + ac1;

  for(int k0 = 0; k0 < K; k0 += 32){
    __builtin_amdgcn_global_load_lds((const AS1 uint_t*)(Ag0 + k0),
                                     (AS3 uint_t*)(As + ch0*8), 16, 0, 0);
    __builtin_amdgcn_global_load_lds((const AS1 uint_t*)(Ag1 + k0),
                                     (AS3 uint_t*)(As + ch1*8), 16, 0, 0);
    __builtin_amdgcn_global_load_lds((const AS1 uint_t*)(Bg0 + k0),
                                     (AS3 uint_t*)(Bs + ch0*8), 16, 0, 0);
    __builtin_amdgcn_global_load_lds((const AS1 uint_t*)(Bg1 + k0),
                                     (AS3 uint_t*)(Bs + ch1*8), 16, 0, 0);
    __syncthreads();

    bf16x8 a[4], b[4];
    #pragma unroll
    for(int i=0;i<4;i++) a[i] = *(const bf16x8*)&As[(wr + i*16 + l15)*32 + quad*8];
    #pragma unroll
    for(int j=0;j<4;j++) b[j] = *(const bf16x8*)&Bs[(wc + j*16 + l15)*32 + quad*8];
    #pragma unroll
    for(int i=0;i<4;i++)
      #pragma unroll
      for(int j=0;j<4;j++)
        acc[i][j] = __builtin_amdgcn_mfma_f32_16x16x32_bf16(a[i], b[j], acc[i][j], 0, 0, 0);
    __syncthreads();
  }

  // epilogue: C/D layout col=lane&15, row=quad*4+reg
  int h = bn >> 7;
  float bv4[4];
  #pragma unroll
  for(int j=0;j<4;j++){
    int gc = bn + wc + j*16 + l15;
    bv4[j] = bias ? bias[gc] : 0.f;
  }
  ushort_t* Ct = smem;
  int myp = w >> 1;
  #pragma unroll
  for(int p=0;p<2;p++){
    if(myp == p){
      #pragma unroll
      for(int i=0;i<4;i++)
        #pragma unroll
        for(int r=0;r<4;r++){
          int row = i*16 + quad*4 + r;   // 0..63 local
          #pragma unroll
          for(int j=0;j<4;j++)
            Ct[row*CTS + wc + j*16 + l15] = f2bf(acc[i][j][r] + bv4[j]);
        }
    }
    __syncthreads();
    #pragma unroll
    for(int k=0;k<4;k++){
      int c = tid + 256*k;
      int row = c >> 4, o16 = c & 15;
      int gr = bm + p*64 + row;
      if(gr < M)
        *(uint4*)(Cb + (size_t)gr*N + bn + o16*8) = *(const uint4*)&Ct[row*CTS + o16*8];
    }
    if(atts){
      int row = tid >> 2, qtr = tid & 3;
      int gr = bm + p*64 + row;
      float sp = 0.f, dp = 0.f;
      const float2* asp = (const float2*)(atts + h*CC) + qtr*16;
      const float2* adp = (const float2*)(attd + h*CC) + qtr*16;
      const uint_t* cr = (const uint_t*)smem + ((row*CTS) >> 1) + qtr*16;
      #pragma unroll
      for(int c2=0;c2<16;c2++){
        uint_t u = cr[c2];
        float2 a2 = asp[c2], d2 = adp[c2];
        sp = fmaf(bf_lo(u), a2.x, fmaf(bf_hi(u), a2.y, sp));
        dp = fmaf(bf_lo(u), d2.x, fmaf(bf_hi(u), d2.y, dp));
      }
      sp += __shfl_xor(sp, 1); sp += __shfl_xor(sp, 2);
      dp += __shfl_xor(dp, 1); dp += __shfl_xor(dp, 2);
      if(qtr == 0 && gr < M){ a_s[gr*6 + h] = sp; a_d[gr*6 + h] = dp; }
    }
    __syncthreads();
  }
}

// ---------- linear-head GEMM, K-split for occupancy ----------
// zs[kc][MP,CC] = yB[MP, kc*192 : +192] @ linWt[CC, same]^T   (grid 4 x 158)
#define KS 4
#define KCH 192
__global__ __launch_bounds__(256) void gemmL(const ushort_t* __restrict__ A,   // yB [MP,FF]
                                             const ushort_t* __restrict__ Bt,  // linWt [CC,FF]
                                             float* __restrict__ zs){
  __shared__ ushort_t As[64*32];
  __shared__ ushort_t Bs[128*32];
  int tid = threadIdx.x;
  int kc0 = blockIdx.x*KCH;
  int bm = blockIdx.y*64;
  int w = tid >> 6, lane = tid & 63;
  int wr = (w >> 1)*32, wc = (w & 1)*64;
  int quad = lane >> 4, l15 = lane & 15;

  f32x4 acc[2][4];
  #pragma unroll
  for(int i=0;i<2;i++)
    #pragma unroll
    for(int j=0;j<4;j++) acc[i][j] = (f32x4){0.f,0.f,0.f,0.f};

  int ch0 = tid, ch1 = tid + 256;
  const ushort_t* Ag  = A  + (size_t)(bm + (ch0 >> 2))*FF + kc0 + ((ch0 & 3) << 3);
  const ushort_t* Bg0 = Bt + (size_t)(ch0 >> 2)*FF + kc0 + ((ch0 & 3) << 3);
  const ushort_t* Bg1 = Bt + (size_t)(ch1 >> 2)*FF + kc0 + ((ch1 & 3) << 3);

  for(int k0 = 0; k0 < KCH; k0 += 32){
    __builtin_amdgcn_global_load_lds((const AS1 uint_t*)(Ag + k0),
                                     (AS3 uint_t*)(As + ch0*8), 16, 0, 0);
    __builtin_amdgcn_global_load_lds((const AS1 uint_t*)(Bg0 + k0),
                                     (AS3 uint_t*)(Bs + ch0*8), 16, 0, 0);
    __builtin_amdgcn_global_load_lds((const AS1 uint_t*)(Bg1 + k0),
                                     (AS3 uint_t*)(Bs + ch1*8), 16, 0, 0);
    __syncthreads();
    bf16x8 a[2], b[4];
    #pragma unroll
    for(int i=0;i<2;i++) a[i] = *(const bf16x8*)&As[(wr + i*16 + l15)*32 + quad*8];
    #pragma unroll
    for(int j=0;j<4;j++) b[j] = *(const bf16x8*)&Bs[(wc + j*16 + l15)*32 + quad*8];
    #pragma unroll
    for(int i=0;i<2;i++)
      #pragma unroll
      for(int j=0;j<4;j++)
        acc[i][j] = __builtin_amdgcn_mfma_f32_16x16x32_bf16(a[i], b[j], acc[i][j], 0, 0, 0);
    __syncthreads();
  }

  float* zp = zs + ((size_t)blockIdx.x*MP + bm)*CC;
  #pragma unroll
  for(int i=0;i<2;i++)
    #pragma unroll
    for(int r=0;r<4;r++){
      int row = wr + i*16 + quad*4 + r;
      #pragma unroll
      for(int j=0;j<4;j++)
        zp[row*CC + wc + j*16 + l15] = acc[i][j][r];
    }
}

// ---------- pool: sum K-splits + bias, per-graph segment max (16 rows/block) ----------
#define PR 16
__global__ __launch_bounds__(128) void poolz(const float* __restrict__ zs,
                                             const float* __restrict__ bias,
                                             const int* __restrict__ ibatch,
                                             unsigned* __restrict__ outEnc){
  int c = threadIdx.x;
  int r0 = blockIdx.x*PR;
  int r1 = r0 + PR;                        // PR divides NN exactly (625*16=10000)
  float bv = bias[c];
  const float* z0 = zs;
  const float* z1 = zs + (size_t)MP*CC;
  const float* z2 = zs + (size_t)2*MP*CC;
  const float* z3 = zs + (size_t)3*MP*CC;
  int g = ibatch[r0];
  float m = -__builtin_inff();
  for(int r = r0; r < r1; r++){
    size_t o = (size_t)r*CC + c;
    float v = z0[o] + z1[o] + z2[o] + z3[o] + bv;
    int gr = ibatch[r];
    if(gr != g){ atomicMax(outEnc + g*CC + c, fenc(m)); g = gr; m = -__builtin_inff(); }
    m = fmaxf(m, v);
  }
  atomicMax(outEnc + g*CC + c, fenc(m));
}

__global__ __launch_bounds__(256) void decode_out(const unsigned* __restrict__ outEnc,
                                                  float* __restrict__ out){
  int i = blockIdx.x*256 + threadIdx.x;
  if(i < BB*CC) out[i] = fdec(outEnc[i]);
}

// ---------- CSR aggregation, inline softmax, 2 edge-halves per node (768 thr) ----------
// y[n,:] = relu( (1/sum_e w_e) * sum_e w_e*hx[src_e] + bias ),
// w_e = exp(leaky_relu(a_s[src_e,h] + a_d[n,h]))   (no max-sub; logits O(1))
// Halves process disjoint edge sublists with clean chunk loops; LDS combine.
__global__ __launch_bounds__(768) void aggregate(const ushort_t* __restrict__ hx,
                                                 const float* __restrict__ a_s,
                                                 const float* __restrict__ a_d,
                                                 const int* __restrict__ row_start,
                                                 const int* __restrict__ csr_src,
                                                 const float* __restrict__ bias,
                                                 ushort_t* __restrict__ y){
  __shared__ float red[3][384];
  int n = blockIdx.x, t = threadIdx.x;
  int half = (t >= 384);
  int tt = half ? t - 384 : t;                       // channel-pair id 0..383
  int h = tt >> 6;                                   // head (wave-uniform)
  int E0 = row_start[n], E1 = row_start[n+1];
  int mid = E0 + ((E1 - E0 + 1) >> 1);
  int e0 = half ? mid : E0;
  int e1 = half ? E1  : mid;
  float adv = a_d[n*6 + h];
  float a0 = 0.f, a1 = 0.f, wsum = 0.f;
  int i = e0;
  for(; i + 8 <= e1; i += 8){
    int s[8]; float wv[8]; uint_t u[8];
    #pragma unroll
    for(int q=0;q<8;q++) s[q] = csr_src[i+q];
    #pragma unroll
    for(int q=0;q<8;q++) wv[q] = a_s[s[q]*6 + h];
    #pragma unroll
    for(int q=0;q<8;q++) u[q] = ((const uint_t*)(hx + (size_t)s[q]*FF))[tt];
    #pragma unroll
    for(int q=0;q<8;q++){
      float v = wv[q] + adv;
      v = v > 0.f ? v : 0.2f * v;
      float wq = __expf(v);
      wsum += wq;
      a0 = fmaf(wq, bf_lo(u[q]), a0); a1 = fmaf(wq, bf_hi(u[q]), a1);
    }
  }
  if(i + 4 <= e1){
    int s[4]; float wv[4]; uint_t u[4];
    #pragma unroll
    for(int q=0;q<4;q++) s[q] = csr_src[i+q];
    #pragma unroll
    for(int q=0;q<4;q++) wv[q] = a_s[s[q]*6 + h];
    #pragma unroll
    for(int q=0;q<4;q++) u[q] = ((const uint_t*)(hx + (size_t)s[q]*FF))[tt];
    #pragma unroll
    for(int q=0;q<4;q++){
      float v = wv[q] + adv;
      v = v > 0.f ? v : 0.2f * v;
      float wq = __expf(v);
      wsum += wq;
      a0 = fmaf(wq, bf_lo(u[q]), a0); a1 = fmaf(wq, bf_hi(u[q]), a1);
    }
    i += 4;
  }
  for(; i < e1; i++){
    int s = csr_src[i];
    float v = a_s[s*6 + h] + adv;
    v = v > 0.f ? v : 0.2f * v;
    float wq = __expf(v);
    wsum += wq;
    uint_t u = ((const uint_t*)(hx + (size_t)s*FF))[tt];
    a0 = fmaf(wq, bf_lo(u), a0); a1 = fmaf(wq, bf_hi(u), a1);
  }
  if(half){
    red[0][tt] = a0; red[1][tt] = a1; red[2][tt] = wsum;
  }
  __syncthreads();
  if(!half){
    a0 += red[0][tt]; a1 += red[1][tt]; wsum += red[2][tt];
    float inv = 1.f/wsum;
    float2 bv = ((const float2*)bias)[tt];
    float v0 = a0*inv + bv.x;
    float v1 = a1*inv + bv.y;
    v0 = v0 > 0.f ? v0 : 0.f;
    v1 = v1 > 0.f ? v1 : 0.f;
    ((uint_t*)(y + (size_t)n*FF))[tt] = (uint_t)f2bf(v0) | ((uint_t)f2bf(v1) << 16);
  }
}

// ---------- batch-norm stats (bf16 input) ----------
__global__ __launch_bounds__(384) void bn_stats(const ushort_t* __restrict__ y,
                                                float* __restrict__ sums,
                                                float* __restrict__ sumsq){
  int t = threadIdx.x;
  float s0=0.f,s1=0.f,q0=0.f,q1=0.f;
  for(int n = blockIdx.x; n < NN; n += gridDim.x){
    uint_t u = ((const uint_t*)(y + (size_t)n*FF))[t];
    float lo = bf_lo(u), hi = bf_hi(u);
    s0 += lo; q0 += lo*lo;
    s1 += hi; q1 += hi*hi;
  }
  atomicAdd(sums + 2*t,     s0); atomicAdd(sumsq + 2*t,     q0);
  atomicAdd(sums + 2*t + 1, s1); atomicAdd(sumsq + 2*t + 1, q1);
}

extern "C" void kernel_launch(void* const* d_in, const int* in_sizes, int n_in,
                              void* d_out, int out_size, void* d_ws, size_t ws_size,
                              hipStream_t stream){
  const float* feat  = (const float*)d_in[0];
  const int*   adj   = (const int*)d_in[1];
  const int*   ibatch= (const int*)d_in[2];
  const float* W1    = (const float*)d_in[3];
  const float* atts1 = (const float*)d_in[4];
  const float* attd1 = (const float*)d_in[5];
  const float* b1    = (const float*)d_in[6];
  const float* g1    = (const float*)d_in[7];
  const float* be1   = (const float*)d_in[8];
  const float* W2    = (const float*)d_in[9];
  const float* atts2 = (const float*)d_in[10];
  const float* attd2 = (const float*)d_in[11];
  const float* b2    = (const float*)d_in[12];
  const float* g2    = (const float*)d_in[13];
  const float* be2   = (const float*)d_in[14];
  const float* linW  = (const float*)d_in[15];
  const float* linb  = (const float*)d_in[16];
  float* out = (float*)d_out;

  size_t off = 0;
  auto alloc = [&](size_t bytes) -> void* {
    void* p = (char*)d_ws + off;
    off += (bytes + 255) & ~(size_t)255;
    return p;
  };
  // ---- zero-init region (single small memset) ----
  size_t zoff0 = off;
  int*      deg     = (int*)alloc((size_t)NN*4);
  float*    sumsA   = (float*)alloc((size_t)2*FF*4);   // [sums | sumsq]
  float*    sumsB   = (float*)alloc((size_t)2*FF*4);
  float*    bias2p  = (float*)alloc((size_t)FF*4);
  float*    biasLp  = (float*)alloc((size_t)CC*4);
  unsigned* outEnc  = (unsigned*)alloc((size_t)BB*CC*4);
  size_t zbytes = off - zoff0;
  // ---- rest ----
  ushort_t* hx      = (ushort_t*)alloc((size_t)NN*FF*2);   // bf16 pre-aggregation features
  ushort_t* yB      = (ushort_t*)alloc((size_t)MP*FF*2);   // bf16 post-aggregation activations
  ushort_t* featB   = (ushort_t*)alloc((size_t)MP*INC*2);
  ushort_t* W1t     = (ushort_t*)alloc((size_t)FF*INC*2);
  ushort_t* W2t     = (ushort_t*)alloc((size_t)FF*FF*2);
  ushort_t* linWt   = (ushort_t*)alloc((size_t)CC*FF*2);
  float*    zs      = (float*)alloc((size_t)KS*MP*CC*4);   // K-split partial products
  float*    a_s     = (float*)alloc((size_t)NN*6*4);
  float*    a_d     = (float*)alloc((size_t)NN*6*4);
  int*      row_start=(int*)alloc((size_t)(NN+1)*4);
  int*      pos     = (int*)alloc((size_t)NN*4);
  int*      csr_src = (int*)alloc((size_t)ETOT*4);

  const int EB = (ETOT + 255)/256;

  hipMemsetAsync((char*)d_ws + zoff0, 0, zbytes, stream);

  // fused prep: count_deg + W1 transpose + feat convert
  prep<<<PREP_CNT + PREP_TR + PREP_CVT,256,0,stream>>>(adj, deg, W1, W1t, feat, featB);
  scan_deg<<<1,1024,0,stream>>>(deg, row_start, pos);
  scatter_edges<<<EB,256,0,stream>>>(adj, pos, csr_src);

  // ---- conv1 (attention dots fused into GEMM epilogue; softmax inline in aggregate) ----
  gemm_bt<<<dim3(FF/128, MP/128),256,0,stream>>>(featB, W1t, hx, NN, FF, INC,
                                                 nullptr, atts1, attd1, a_s, a_d);
  aggregate<<<NN,768,0,stream>>>(hx, a_s, a_d, row_start, csr_src, b1, yB);
  bn_stats<<<256,384,0,stream>>>(yB, sumsA, sumsA + FF);

  // ---- conv2 (BN1 folded: fused scaled-transpose + bias fold) ----
  wfold<<<(FF/32)*(FF/32) + (FF/64)*3,256,0,stream>>>(W2, FF, FF, sumsA, sumsA + FF, g1, be1,
                                                      nullptr, W2t, bias2p);
  gemm_bt<<<dim3(FF/128, MP/128),256,0,stream>>>(yB, W2t, hx, NN, FF, FF,
                                                 bias2p, atts2, attd2, a_s, a_d);
  aggregate<<<NN,768,0,stream>>>(hx, a_s, a_d, row_start, csr_src, b2, yB);
  bn_stats<<<256,384,0,stream>>>(yB, sumsB, sumsB + FF);

  // ---- linear head (BN2 folded), K-split GEMM + segment max pool ----
  wfold<<<(FF/32)*(CC/32) + (FF/64)*1,256,0,stream>>>(linW, FF, CC, sumsB, sumsB + FF, g2, be2,
                                                      linb, linWt, biasLp);
  gemmL<<<dim3(KS, MP/64),256,0,stream>>>(yB, linWt, zs);
  poolz<<<NN/PR,128,0,stream>>>(zs, biasLp, ibatch, outEnc);
  decode_out<<<(BB*CC+255)/256,256,0,stream>>>(outEnc, out);
}

// Round 15
// 318.083 us; speedup vs baseline: 1.1609x; 1.1609x over previous
//
#include <hip/hip_runtime.h>

#define NN 10000
#define MP 10112      // 79*128, padded row count for MFMA GEMM A-tiles
#define EE 100000
#define ETOT 110000   // EE + NN self loops
#define INC 256
#define HH 6
#define CC 128
#define FF 768        // HH*CC
#define BB 64
#define BN_EPS 1e-5f

typedef unsigned short ushort_t;
typedef unsigned int uint_t;
typedef __attribute__((ext_vector_type(8))) short bf16x8;
typedef __attribute__((ext_vector_type(4))) float f32x4;
#define AS1 __attribute__((address_space(1)))
#define AS3 __attribute__((address_space(3)))

// ---------- float <-> order-preserving uint encoding (for atomicMax on float) ----------
// fenc(v) > 0 for every non-NaN v, so zero-initialized buffer acts as -inf.
__device__ __forceinline__ unsigned fenc(float v){
  unsigned u = __float_as_uint(v);
  return (u & 0x80000000u) ? ~u : (u | 0x80000000u);
}
__device__ __forceinline__ float fdec(unsigned u){
  return (u & 0x80000000u) ? __uint_as_float(u & 0x7FFFFFFFu) : __uint_as_float(~u);
}

__device__ __forceinline__ ushort_t f2bf(float v){   // RNE fp32 -> bf16
  unsigned u = __float_as_uint(v);
  u += 0x7FFFu + ((u >> 16) & 1u);
  return (ushort_t)(u >> 16);
}
__device__ __forceinline__ float bf_lo(uint_t u){ return __uint_as_float(u << 16); }
__device__ __forceinline__ float bf_hi(uint_t u){ return __uint_as_float(u & 0xFFFF0000u); }

__device__ __forceinline__ float bn_scale(const float* sums, const float* sumsq,
                                          const float* g, int k){
  float mu  = sums[k] * (1.f/NN);
  float var = sumsq[k] * (1.f/NN) - mu*mu;
  return g[k] * rsqrtf(var + BN_EPS);
}

// ---------- prep: count_deg + transpose(W1) + feat->bf16, fused (independent parts) ----------
#define PREP_CNT 430                 // ceil(ETOT/256)
#define PREP_TR  (24*8)              // (FF/32)*(INC/32)
#define PREP_CVT 2500                // NN*INC/4/256
__global__ __launch_bounds__(256) void prep(const int* __restrict__ adj, int* __restrict__ deg,
                                            const float* __restrict__ W1, ushort_t* __restrict__ W1t,
                                            const float* __restrict__ feat, ushort_t* __restrict__ featB){
  __shared__ ushort_t tile[32][33];
  int bid = blockIdx.x, tid = threadIdx.x;
  if(bid < PREP_CNT){
    int k = bid*256 + tid;
    if(k < ETOT){
      int d = (k < EE) ? adj[EE + k] : (k - EE);
      atomicAdd(deg + d, 1);
    }
  } else if(bid < PREP_CNT + PREP_TR){
    int b = bid - PREP_CNT;
    int nb = (b % 24)*32, kb = (b / 24)*32;    // K=INC rows, N=FF cols
    int tx = tid & 31, ty = tid >> 5;
    #pragma unroll
    for(int r = ty; r < 32; r += 8)
      tile[tx][r] = f2bf(W1[(size_t)(kb + r)*FF + nb + tx]);
    __syncthreads();
    #pragma unroll
    for(int r = ty; r < 32; r += 8)
      W1t[(size_t)(nb + r)*INC + kb + tx] = tile[r][tx];
  } else {
    int i = (bid - PREP_CNT - PREP_TR)*256 + tid;   // i < NN*INC/4 guaranteed by grid
    float4 v = ((const float4*)feat)[i];
    ushort4 o;
    o.x = f2bf(v.x); o.y = f2bf(v.y); o.z = f2bf(v.z); o.w = f2bf(v.w);
    ((ushort4*)featB)[i] = o;
  }
}

// ---------- CSR build ----------
__global__ __launch_bounds__(1024) void scan_deg(const int* __restrict__ deg,
                                                 int* __restrict__ row_start,
                                                 int* __restrict__ pos){
  __shared__ int wsum[16];
  __shared__ int wexcl[16];
  __shared__ int carry, ctot;
  int t = threadIdx.x, wave = t >> 6, lane = t & 63;
  if(t == 0) carry = 0;
  __syncthreads();
  for(int base = 0; base < NN; base += 1024){
    int i = base + t;
    int v = (i < NN) ? deg[i] : 0;
    int s = v;
    #pragma unroll
    for(int off = 1; off < 64; off <<= 1){ int x = __shfl_up(s, off); if(lane >= off) s += x; }
    if(lane == 63) wsum[wave] = s;
    __syncthreads();
    if(t < 16){
      int ws = wsum[t], sc = ws;
      #pragma unroll
      for(int off = 1; off < 16; off <<= 1){ int x = __shfl_up(sc, off); if(t >= off) sc += x; }
      wexcl[t] = sc - ws;
      if(t == 15) ctot = sc;
    }
    __syncthreads();
    int c = carry;
    if(i < NN){ int excl = c + wexcl[wave] + s - v; row_start[i] = excl; pos[i] = excl; }
    __syncthreads();
    if(t == 0) carry = c + ctot;
  }
  __syncthreads();
  if(t == 0) row_start[NN] = carry;
}

__global__ __launch_bounds__(256) void scatter_edges(const int* __restrict__ adj,
                                                     int* __restrict__ pos,
                                                     int* __restrict__ csr_src){
  int k = blockIdx.x*256 + threadIdx.x;
  if(k >= ETOT) return;
  int s, d;
  if(k < EE){ s = adj[k]; d = adj[EE + k]; } else { s = k - EE; d = s; }
  int i = atomicAdd(pos + d, 1);
  csr_src[i] = s;
}

// ---------- wfold: BN-scaled transpose + BN-shift bias fold, fused ----------
__global__ __launch_bounds__(256) void wfold(const float* __restrict__ W,
                                             int K, int N,
                                             const float* __restrict__ sums,
                                             const float* __restrict__ sumsq,
                                             const float* __restrict__ g,
                                             const float* __restrict__ be,
                                             const float* __restrict__ base,
                                             ushort_t* __restrict__ Wt,
                                             float* __restrict__ biasOut){
  __shared__ ushort_t tile[32][33];
  int nT = (K >> 5)*(N >> 5);
  int bid = blockIdx.x, tid = threadIdx.x;
  if(bid < nT){
    int nb = (bid % (N >> 5))*32, kb = (bid / (N >> 5))*32;
    int tx = tid & 31, ty = tid >> 5;
    #pragma unroll
    for(int r = ty; r < 32; r += 8){
      int k = kb + r;
      tile[tx][r] = f2bf(W[(size_t)k*N + nb + tx] * bn_scale(sums, sumsq, g, k));
    }
    __syncthreads();
    #pragma unroll
    for(int r = ty; r < 32; r += 8)
      Wt[(size_t)(nb + r)*K + kb + tx] = tile[r][tx];
  } else {
    int b = bid - nT;
    int oChunks = (N + 255) >> 8;
    int kc = b / oChunks, oc = b % oChunks;
    int o = oc*256 + tid;
    if(o >= N) return;
    int k0 = kc*64, k1 = k0 + 64;
    float s = 0.f;
    for(int k = k0; k < k1; k++){
      float mu = sums[k] * (1.f/NN);
      float sc = bn_scale(sums, sumsq, g, k);
      s = fmaf(be[k] - mu*sc, W[(size_t)k*N + o], s);
    }
    if(k0 == 0 && base) s += base[o];
    atomicAdd(biasOut + o, s);
  }
}

// ---------- bf16 MFMA GEMM + fused attention-dot epilogue (conv layers) ----------
// C[M,N] = A[MP,K] * Bt[N,K]^T (+bias); block cols = one head when atts!=null.
// C-store: 2-pass LDS staging (64 rows x 128 cols, stride 136) -> dwordx4 stores;
// att dots read rows back from LDS (4 thr/row + 2 shfl).
#define CTS 136
__global__ __launch_bounds__(256) void gemm_bt(const ushort_t* __restrict__ A,
                                               const ushort_t* __restrict__ Bt,
                                               ushort_t* __restrict__ Cb,
                                               int M, int N, int K,
                                               const float* __restrict__ bias,
                                               const float* __restrict__ atts,
                                               const float* __restrict__ attd,
                                               float* __restrict__ a_s,
                                               float* __restrict__ a_d){
  __shared__ ushort_t smem[8704];           // As[4096] | Bs[4096]; reused as Ct[64*136]
  ushort_t* As = smem;
  ushort_t* Bs = smem + 4096;
  int tid = threadIdx.x;
  int bm = blockIdx.y*128, bn = blockIdx.x*128;
  int w = tid >> 6, lane = tid & 63;
  int wr = (w >> 1)*64, wc = (w & 1)*64;
  int quad = lane >> 4, l15 = lane & 15;

  f32x4 acc[4][4];
  #pragma unroll
  for(int i=0;i<4;i++)
    #pragma unroll
    for(int j=0;j<4;j++) acc[i][j] = (f32x4){0.f,0.f,0.f,0.f};

  int ch0 = tid, ch1 = tid + 256;
  int ar0 = ch0 >> 2, ac0 = (ch0 & 3) << 3;
  int ar1 = ch1 >> 2, ac1 = (ch1 & 3) << 3;
  const ushort_t* Ag0 = A + (size_t)(bm + ar0)*K + ac0;
  const ushort_t* Ag1 = A + (size_t)(bm + ar1)*K + ac1;
  const ushort_t* Bg0 = Bt + (size_t)(bn + ar0)*K + ac0;
  const ushort_t* Bg1 = Bt + (size_t)(bn + ar1)*K + ac1;

  for(int k0 = 0; k0 < K; k0 += 32){
    __builtin_amdgcn_global_load_lds((const AS1 uint_t*)(Ag0 + k0),
                                     (AS3 uint_t*)(As + ch0*8), 16, 0, 0);
    __builtin_amdgcn_global_load_lds((const AS1 uint_t*)(Ag1 + k0),
                                     (AS3 uint_t*)(As + ch1*8), 16, 0, 0);
    __builtin_amdgcn_global_load_lds((const AS1 uint_t*)(Bg0 + k0),
                                     (AS3 uint_t*)(Bs + ch0*8), 16, 0, 0);
    __builtin_amdgcn_global_load_lds((const AS1 uint_t*)(Bg1 + k0),
                                     (AS3 uint_t*)(Bs + ch1*8), 16, 0, 0);
    __syncthreads();

    bf16x8 a[4], b[4];
    #pragma unroll
    for(int i=0;i<4;i++) a[i] = *(const bf16x8*)&As[(wr + i*16 + l15)*32 + quad*8];
    #pragma unroll
    for(int j=0;j<4;j++) b[j] = *(const bf16x8*)&Bs[(wc + j*16 + l15)*32 + quad*8];
    #pragma unroll
    for(int i=0;i<4;i++)
      #pragma unroll
      for(int j=0;j<4;j++)
        acc[i][j] = __builtin_amdgcn_mfma_f32_16x16x32_bf16(a[i], b[j], acc[i][j], 0, 0, 0);
    __syncthreads();
  }

  // epilogue: C/D layout col=lane&15, row=quad*4+reg
  int h = bn >> 7;
  float bv4[4];
  #pragma unroll
  for(int j=0;j<4;j++){
    int gc = bn + wc + j*16 + l15;
    bv4[j] = bias ? bias[gc] : 0.f;
  }
  ushort_t* Ct = smem;
  int myp = w >> 1;
  #pragma unroll
  for(int p=0;p<2;p++){
    if(myp == p){
      #pragma unroll
      for(int i=0;i<4;i++)
        #pragma unroll
        for(int r=0;r<4;r++){
          int row = i*16 + quad*4 + r;   // 0..63 local
          #pragma unroll
          for(int j=0;j<4;j++)
            Ct[row*CTS + wc + j*16 + l15] = f2bf(acc[i][j][r] + bv4[j]);
        }
    }
    __syncthreads();
    #pragma unroll
    for(int k=0;k<4;k++){
      int c = tid + 256*k;
      int row = c >> 4, o16 = c & 15;
      int gr = bm + p*64 + row;
      if(gr < M)
        *(uint4*)(Cb + (size_t)gr*N + bn + o16*8) = *(const uint4*)&Ct[row*CTS + o16*8];
    }
    if(atts){
      int row = tid >> 2, qtr = tid & 3;
      int gr = bm + p*64 + row;
      float sp = 0.f, dp = 0.f;
      const float2* asp = (const float2*)(atts + h*CC) + qtr*16;
      const float2* adp = (const float2*)(attd + h*CC) + qtr*16;
      const uint_t* cr = (const uint_t*)smem + ((row*CTS) >> 1) + qtr*16;
      #pragma unroll
      for(int c2=0;c2<16;c2++){
        uint_t u = cr[c2];
        float2 a2 = asp[c2], d2 = adp[c2];
        sp = fmaf(bf_lo(u), a2.x, fmaf(bf_hi(u), a2.y, sp));
        dp = fmaf(bf_lo(u), d2.x, fmaf(bf_hi(u), d2.y, dp));
      }
      sp += __shfl_xor(sp, 1); sp += __shfl_xor(sp, 2);
      dp += __shfl_xor(dp, 1); dp += __shfl_xor(dp, 2);
      if(qtr == 0 && gr < M){ a_s[gr*6 + h] = sp; a_d[gr*6 + h] = dp; }
    }
    __syncthreads();
  }
}

// ---------- linear-head GEMM, K-split for occupancy ----------
// zs[kc][MP,CC] = yB[MP, kc*192 : +192] @ linWt[CC, same]^T   (grid 4 x 158)
#define KS 4
#define KCH 192
__global__ __launch_bounds__(256) void gemmL(const ushort_t* __restrict__ A,   // yB [MP,FF]
                                             const ushort_t* __restrict__ Bt,  // linWt [CC,FF]
                                             float* __restrict__ zs){
  __shared__ ushort_t As[64*32];
  __shared__ ushort_t Bs[128*32];
  int tid = threadIdx.x;
  int kc0 = blockIdx.x*KCH;
  int bm = blockIdx.y*64;
  int w = tid >> 6, lane = tid & 63;
  int wr = (w >> 1)*32, wc = (w & 1)*64;
  int quad = lane >> 4, l15 = lane & 15;

  f32x4 acc[2][4];
  #pragma unroll
  for(int i=0;i<2;i++)
    #pragma unroll
    for(int j=0;j<4;j++) acc[i][j] = (f32x4){0.f,0.f,0.f,0.f};

  int ch0 = tid, ch1 = tid + 256;
  const ushort_t* Ag  = A  + (size_t)(bm + (ch0 >> 2))*FF + kc0 + ((ch0 & 3) << 3);
  const ushort_t* Bg0 = Bt + (size_t)(ch0 >> 2)*FF + kc0 + ((ch0 & 3) << 3);
  const ushort_t* Bg1 = Bt + (size_t)(ch1 >> 2)*FF + kc0 + ((ch1 & 3) << 3);

  for(int k0 = 0; k0 < KCH; k0 += 32){
    __builtin_amdgcn_global_load_lds((const AS1 uint_t*)(Ag + k0),
                                     (AS3 uint_t*)(As + ch0*8), 16, 0, 0);
    __builtin_amdgcn_global_load_lds((const AS1 uint_t*)(Bg0 + k0),
                                     (AS3 uint_t*)(Bs + ch0*8), 16, 0, 0);
    __builtin_amdgcn_global_load_lds((const AS1 uint_t*)(Bg1 + k0),
                                     (AS3 uint_t*)(Bs + ch1*8), 16, 0, 0);
    __syncthreads();
    bf16x8 a[2], b[4];
    #pragma unroll
    for(int i=0;i<2;i++) a[i] = *(const bf16x8*)&As[(wr + i*16 + l15)*32 + quad*8];
    #pragma unroll
    for(int j=0;j<4;j++) b[j] = *(const bf16x8*)&Bs[(wc + j*16 + l15)*32 + quad*8];
    #pragma unroll
    for(int i=0;i<2;i++)
      #pragma unroll
      for(int j=0;j<4;j++)
        acc[i][j] = __builtin_amdgcn_mfma_f32_16x16x32_bf16(a[i], b[j], acc[i][j], 0, 0, 0);
    __syncthreads();
  }

  float* zp = zs + ((size_t)blockIdx.x*MP + bm)*CC;
  #pragma unroll
  for(int i=0;i<2;i++)
    #pragma unroll
    for(int r=0;r<4;r++){
      int row = wr + i*16 + quad*4 + r;
      #pragma unroll
      for(int j=0;j<4;j++)
        zp[row*CC + wc + j*16 + l15] = acc[i][j][r];
    }
}

// ---------- pool: sum K-splits + bias, per-graph segment max (16 rows/block) ----------
#define PR 16
__global__ __launch_bounds__(128) void poolz(const float* __restrict__ zs,
                                             const float* __restrict__ bias,
                                             const int* __restrict__ ibatch,
                                             unsigned* __restrict__ outEnc){
  int c = threadIdx.x;
  int r0 = blockIdx.x*PR;
  int r1 = r0 + PR; if(r1 > NN) r1 = NN;
  if(r0 >= NN) return;
  float bv = bias[c];
  const float* z0 = zs;
  const float* z1 = zs + (size_t)MP*CC;
  const float* z2 = zs + (size_t)2*MP*CC;
  const float* z3 = zs + (size_t)3*MP*CC;
  int g = ibatch[r0];
  float m = -__builtin_inff();
  for(int r = r0; r < r1; r++){
    size_t o = (size_t)r*CC + c;
    float v = z0[o] + z1[o] + z2[o] + z3[o] + bv;
    int gr = ibatch[r];
    if(gr != g){ atomicMax(outEnc + g*CC + c, fenc(m)); g = gr; m = -__builtin_inff(); }
    m = fmaxf(m, v);
  }
  atomicMax(outEnc + g*CC + c, fenc(m));
}

__global__ __launch_bounds__(256) void decode_out(const unsigned* __restrict__ outEnc,
                                                  float* __restrict__ out){
  int i = blockIdx.x*256 + threadIdx.x;
  if(i < BB*CC) out[i] = fdec(outEnc[i]);
}

// ---------- CSR aggregation with INLINE softmax (R10-proven: chunk-8 + chunk-4 + tail) ----------
// y[n,:] = relu( (1/sum_e w_e) * sum_e w_e*hx[src_e] + bias ),
// w_e = exp(leaky_relu(a_s[src_e,h] + a_d[n,h]))   (no max-sub; logits O(1))
__global__ __launch_bounds__(384) void aggregate(const ushort_t* __restrict__ hx,
                                                 const float* __restrict__ a_s,
                                                 const float* __restrict__ a_d,
                                                 const int* __restrict__ row_start,
                                                 const int* __restrict__ csr_src,
                                                 const float* __restrict__ bias,
                                                 ushort_t* __restrict__ y){
  int n = blockIdx.x, t = threadIdx.x, h = t >> 6;   // thread t owns channels 2t,2t+1
  int e0 = row_start[n], e1 = row_start[n+1];
  float adv = a_d[n*6 + h];                          // wave-uniform
  float a0 = 0.f, a1 = 0.f, wsum = 0.f;
  int i = e0;
  for(; i + 8 <= e1; i += 8){
    int s[8]; float wv[8]; uint_t u[8];
    #pragma unroll
    for(int q=0;q<8;q++) s[q] = csr_src[i+q];
    #pragma unroll
    for(int q=0;q<8;q++) wv[q] = a_s[s[q]*6 + h];
    #pragma unroll
    for(int q=0;q<8;q++) u[q] = ((const uint_t*)(hx + (size_t)s[q]*FF))[t];
    #pragma unroll
    for(int q=0;q<8;q++){
      float v = wv[q] + adv;
      v = v > 0.f ? v : 0.2f * v;
      float wq = __expf(v);
      wsum += wq;
      a0 = fmaf(wq, bf_lo(u[q]), a0); a1 = fmaf(wq, bf_hi(u[q]), a1);
    }
  }
  if(i + 4 <= e1){
    int s[4]; float wv[4]; uint_t u[4];
    #pragma unroll
    for(int q=0;q<4;q++) s[q] = csr_src[i+q];
    #pragma unroll
    for(int q=0;q<4;q++) wv[q] = a_s[s[q]*6 + h];
    #pragma unroll
    for(int q=0;q<4;q++) u[q] = ((const uint_t*)(hx + (size_t)s[q]*FF))[t];
    #pragma unroll
    for(int q=0;q<4;q++){
      float v = wv[q] + adv;
      v = v > 0.f ? v : 0.2f * v;
      float wq = __expf(v);
      wsum += wq;
      a0 = fmaf(wq, bf_lo(u[q]), a0); a1 = fmaf(wq, bf_hi(u[q]), a1);
    }
    i += 4;
  }
  for(; i < e1; i++){
    int s = csr_src[i];
    float v = a_s[s*6 + h] + adv;
    v = v > 0.f ? v : 0.2f * v;
    float wq = __expf(v);
    wsum += wq;
    uint_t u = ((const uint_t*)(hx + (size_t)s*FF))[t];
    a0 = fmaf(wq, bf_lo(u), a0); a1 = fmaf(wq, bf_hi(u), a1);
  }
  float inv = 1.f/wsum;
  float2 bv = ((const float2*)bias)[t];
  float v0 = a0*inv + bv.x;
  float v1 = a1*inv + bv.y;
  v0 = v0 > 0.f ? v0 : 0.f;
  v1 = v1 > 0.f ? v1 : 0.f;
  uint_t p = (uint_t)f2bf(v0) | ((uint_t)f2bf(v1) << 16);
  ((uint_t*)(y + (size_t)n*FF))[t] = p;
}

// ---------- batch-norm stats (bf16 input) ----------
__global__ __launch_bounds__(384) void bn_stats(const ushort_t* __restrict__ y,
                                                float* __restrict__ sums,
                                                float* __restrict__ sumsq){
  int t = threadIdx.x;
  float s0=0.f,s1=0.f,q0=0.f,q1=0.f;
  for(int n = blockIdx.x; n < NN; n += gridDim.x){
    uint_t u = ((const uint_t*)(y + (size_t)n*FF))[t];
    float lo = bf_lo(u), hi = bf_hi(u);
    s0 += lo; q0 += lo*lo;
    s1 += hi; q1 += hi*hi;
  }
  atomicAdd(sums + 2*t,     s0); atomicAdd(sumsq + 2*t,     q0);
  atomicAdd(sums + 2*t + 1, s1); atomicAdd(sumsq + 2*t + 1, q1);
}

extern "C" void kernel_launch(void* const* d_in, const int* in_sizes, int n_in,
                              void* d_out, int out_size, void* d_ws, size_t ws_size,
                              hipStream_t stream){
  const float* feat  = (const float*)d_in[0];
  const int*   adj   = (const int*)d_in[1];
  const int*   ibatch= (const int*)d_in[2];
  const float* W1    = (const float*)d_in[3];
  const float* atts1 = (const float*)d_in[4];
  const float* attd1 = (const float*)d_in[5];
  const float* b1    = (const float*)d_in[6];
  const float* g1    = (const float*)d_in[7];
  const float* be1   = (const float*)d_in[8];
  const float* W2    = (const float*)d_in[9];
  const float* atts2 = (const float*)d_in[10];
  const float* attd2 = (const float*)d_in[11];
  const float* b2    = (const float*)d_in[12];
  const float* g2    = (const float*)d_in[13];
  const float* be2   = (const float*)d_in[14];
  const float* linW  = (const float*)d_in[15];
  const float* linb  = (const float*)d_in[16];
  float* out = (float*)d_out;

  size_t off = 0;
  auto alloc = [&](size_t bytes) -> void* {
    void* p = (char*)d_ws + off;
    off += (bytes + 255) & ~(size_t)255;
    return p;
  };
  // ---- zero-init region (single small memset) ----
  size_t zoff0 = off;
  int*      deg     = (int*)alloc((size_t)NN*4);
  float*    sumsA   = (float*)alloc((size_t)2*FF*4);   // [sums | sumsq]
  float*    sumsB   = (float*)alloc((size_t)2*FF*4);
  float*    bias2p  = (float*)alloc((size_t)FF*4);
  float*    biasLp  = (float*)alloc((size_t)CC*4);
  unsigned* outEnc  = (unsigned*)alloc((size_t)BB*CC*4);
  size_t zbytes = off - zoff0;
  // ---- rest ----
  ushort_t* hx      = (ushort_t*)alloc((size_t)NN*FF*2);   // bf16 pre-aggregation features
  ushort_t* yB      = (ushort_t*)alloc((size_t)MP*FF*2);   // bf16 post-aggregation activations
  ushort_t* featB   = (ushort_t*)alloc((size_t)MP*INC*2);
  ushort_t* W1t     = (ushort_t*)alloc((size_t)FF*INC*2);
  ushort_t* W2t     = (ushort_t*)alloc((size_t)FF*FF*2);
  ushort_t* linWt   = (ushort_t*)alloc((size_t)CC*FF*2);
  float*    zs      = (float*)alloc((size_t)KS*MP*CC*4);   // K-split partial products
  float*    a_s     = (float*)alloc((size_t)NN*6*4);
  float*    a_d     = (float*)alloc((size_t)NN*6*4);
  int*      row_start=(int*)alloc((size_t)(NN+1)*4);
  int*      pos     = (int*)alloc((size_t)NN*4);
  int*      csr_src = (int*)alloc((size_t)ETOT*4);

  const int EB = (ETOT + 255)/256;

  hipMemsetAsync((char*)d_ws + zoff0, 0, zbytes, stream);

  // fused prep: count_deg + W1 transpose + feat convert
  prep<<<PREP_CNT + PREP_TR + PREP_CVT,256,0,stream>>>(adj, deg, W1, W1t, feat, featB);
  scan_deg<<<1,1024,0,stream>>>(deg, row_start, pos);
  scatter_edges<<<EB,256,0,stream>>>(adj, pos, csr_src);

  // ---- conv1 (attention dots fused into GEMM epilogue; softmax inline in aggregate) ----
  gemm_bt<<<dim3(FF/128, MP/128),256,0,stream>>>(featB, W1t, hx, NN, FF, INC,
                                                 nullptr, atts1, attd1, a_s, a_d);
  aggregate<<<NN,384,0,stream>>>(hx, a_s, a_d, row_start, csr_src, b1, yB);
  bn_stats<<<256,384,0,stream>>>(yB, sumsA, sumsA + FF);

  // ---- conv2 (BN1 folded: fused scaled-transpose + bias fold) ----
  wfold<<<(FF/32)*(FF/32) + (FF/64)*3,256,0,stream>>>(W2, FF, FF, sumsA, sumsA + FF, g1, be1,
                                                      nullptr, W2t, bias2p);
  gemm_bt<<<dim3(FF/128, MP/128),256,0,stream>>>(yB, W2t, hx, NN, FF, FF,
                                                 bias2p, atts2, attd2, a_s, a_d);
  aggregate<<<NN,384,0,stream>>>(hx, a_s, a_d, row_start, csr_src, b2, yB);
  bn_stats<<<256,384,0,stream>>>(yB, sumsB, sumsB + FF);

  // ---- linear head (BN2 folded), K-split GEMM + segment max pool ----
  wfold<<<(FF/32)*(CC/32) + (FF/64)*1,256,0,stream>>>(linW, FF, CC, sumsB, sumsB + FF, g2, be2,
                                                      linb, linWt, biasLp);
  gemmL<<<dim3(KS, MP/64),256,0,stream>>>(yB, linWt, zs);
  poolz<<<(NN+PR-1)/PR,128,0,stream>>>(zs, biasLp, ibatch, outEnc);
  decode_out<<<(BB*CC+255)/256,256,0,stream>>>(outEnc, out);
}